// Round 3
// baseline (121.447 us; speedup 1.0000x reference)
//
#include <hip/hip_runtime.h>

// Static shapes: B=16, T=512, D=384 (=96 float4), F=max_len=4096.
#define BB   16
#define TT   512
#define FF   4096
#define DD4  96
#define FPT  32                  // frames per tile
#define TILES (FF / FPT)         // 128 tiles per batch
#define NTHR 512                 // == TT so the R1 scan ports verbatim

// Fused kernel, built from R1-proven pieces only.
// Each block (512 thr) handles one 32-frame tile of one batch:
//  1) R1's Hillis-Steele LDS scan of the batch's 512 durations (proven),
//  2) R1's scatter-style searchsorted, windowed to this tile (proven logic),
//  3) tile copy: 32 frames * 96 float4 = 6 * 512 coalesced float4 stores.
__global__ __launch_bounds__(NTHR) void lenreg_fused_kernel(
    const float4* __restrict__ x, const int* __restrict__ dur,
    float4* __restrict__ out) {
    const int bid  = blockIdx.x;
    const int b    = bid / TILES;
    const int tile = bid - b * TILES;
    const int f0   = tile * FPT;
    const int t    = threadIdx.x;

    __shared__ int s[TT];        // inclusive cumsum of durations
    __shared__ int sidx[FPT];    // phoneme index per frame in tile (-1 = pad)

    // ---- 1) R1's scan, verbatim ----
    const int d = dur[b * TT + t];
    s[t] = d;
    if (t < FPT) sidx[t] = -1;
    __syncthreads();
#pragma unroll
    for (int off = 1; off < TT; off <<= 1) {
        int v = (t >= off) ? s[t - off] : 0;
        __syncthreads();
        s[t] += v;
        __syncthreads();
    }

    // ---- 2) R1's scatter, windowed to [f0, f0+FPT) ----
    const int cum   = s[t];          // inclusive cumsum through phoneme t
    const int start = cum - d;
    int lo = start > f0 ? start : f0;
    int hi = cum < f0 + FPT ? cum : f0 + FPT;
    for (int f = lo; f < hi; ++f) sidx[f - f0] = t;
    __syncthreads();

    // ---- 3) tile copy: 3072 float4 = 6 * 512 ----
    const float4* xb = x + (size_t)b * TT * DD4;
    float4* ob = out + ((size_t)b * FF + f0) * DD4;
#pragma unroll
    for (int k = 0; k < (FPT * DD4) / NTHR; ++k) {   // 6 iterations
        const int pos = k * NTHR + t;
        const int fl  = pos / DD4;                   // frame within tile
        const int c   = pos - fl * DD4;              // float4 column
        const int idx = sidx[fl];
        float4 vv;
        if (idx >= 0) {
            vv = xb[(size_t)idx * DD4 + c];
        } else {
            vv = make_float4(0.f, 0.f, 0.f, 0.f);
        }
        ob[pos] = vv;
    }
}

extern "C" void kernel_launch(void* const* d_in, const int* in_sizes, int n_in,
                              void* d_out, int out_size, void* d_ws, size_t ws_size,
                              hipStream_t stream) {
    const float* x  = (const float*)d_in[0];
    const int* dur  = (const int*)d_in[1];   // int32 on device
    lenreg_fused_kernel<<<BB * TILES, NTHR, 0, stream>>>(
        (const float4*)x, dur, (float4*)d_out);
}

// Round 4
// 117.713 us; speedup vs baseline: 1.0317x; 1.0317x over previous
//
#include <hip/hip_runtime.h>

// Static shapes: B=16, T=512, D=384 (=96 float4), F=max_len=4096.
#define BB   16
#define TT   512
#define FF   4096
#define DD4  96
#define FPT  16                  // frames per gather block
#define TILES (FF / FPT)         // 256 tiles per batch
#define NTHR 256

// Kernel 1 (R1-proven, verbatim): one block per batch. Hillis-Steele LDS scan
// of durations, then scatter phoneme index t into fidx[cum-d .. cum).
// Frames past the total stay -1 (zero-fill in gather).
__global__ __launch_bounds__(TT) void build_idx_kernel(
    const int* __restrict__ dur, int* __restrict__ fidx) {
    const int b = blockIdx.x;
    const int t = threadIdx.x;
    int* fb = fidx + b * FF;

#pragma unroll
    for (int k = 0; k < FF / TT; ++k) fb[k * TT + t] = -1;

    __shared__ int s[TT];
    const int d = dur[b * TT + t];
    s[t] = d;
    __syncthreads();
#pragma unroll
    for (int off = 1; off < TT; off <<= 1) {
        int v = (t >= off) ? s[t - off] : 0;
        __syncthreads();
        s[t] += v;
        __syncthreads();
    }
    const int cum = s[t];            // inclusive cumsum
    const int start = cum - d;
    const int end = cum < FF ? cum : FF;   // max total = 512*7 = 3584 < 4096
    for (int f = start; f < end; ++f) fb[f] = t;
}

// Kernel 2: minimal gather. Thread t owns frame (t>>4), columns (t&15)+16k.
// One fidx load per thread (L1 broadcast x16), no LDS, no barriers,
// 6 independent float4 load/store pairs per thread.
__global__ __launch_bounds__(NTHR) void gather_kernel(
    const float4* __restrict__ x, const int* __restrict__ fidx,
    float4* __restrict__ out) {
    const int bid  = blockIdx.x;
    const int b    = bid / TILES;
    const int tile = bid - b * TILES;
    const int t    = threadIdx.x;
    const int fl   = t >> 4;               // frame within tile, 0..15
    const int c0   = t & 15;               // column group
    const int f    = tile * FPT + fl;

    const int idx = fidx[b * FF + f];
    float4* dst = out + ((size_t)b * FF + f) * DD4;

    if (idx >= 0) {
        const float4* src = x + ((size_t)b * TT + idx) * DD4;
#pragma unroll
        for (int k = 0; k < 6; ++k) dst[c0 + 16 * k] = src[c0 + 16 * k];
    } else {
        const float4 z = make_float4(0.f, 0.f, 0.f, 0.f);
#pragma unroll
        for (int k = 0; k < 6; ++k) dst[c0 + 16 * k] = z;
    }
}

extern "C" void kernel_launch(void* const* d_in, const int* in_sizes, int n_in,
                              void* d_out, int out_size, void* d_ws, size_t ws_size,
                              hipStream_t stream) {
    const float* x = (const float*)d_in[0];
    const int* dur = (const int*)d_in[1];   // int32 on device
    int* fidx = (int*)d_ws;                 // B*F ints = 256 KB scratch

    build_idx_kernel<<<BB, TT, 0, stream>>>(dur, fidx);
    gather_kernel<<<BB * TILES, NTHR, 0, stream>>>(
        (const float4*)x, fidx, (float4*)d_out);
}